// Round 2
// baseline (296.292 us; speedup 1.0000x reference)
//
#include <hip/hip_runtime.h>
#include <hip/hip_bf16.h>

// ---------------------------------------------------------------------------
// AttentionModel B=4,S=2048,E=1024 single-head, fp32 in/out. bf16 MFMA GEMMs.
// R9: R8 with the dead typo'd gload_lds definition removed (compile fix).
//     qkv_proj + scores on the 256x256 8-phase counted-vmcnt template
//     (T3+T4+T5): 512 thr / 8 waves (2x4), BK=64, 128KiB LDS (2 buf x 4
//     half-tiles 128x64), one half staged per phase, vmcnt(6) at ph3/ph7
//     only, raw s_barrier + lgkmcnt(0) + sched_barrier(0) + setprio around
//     each 16-MFMA cluster. Fragment math + XOR-slot swizzle identical to
//     the verified R7 kernel. PV kept as R7 (128^2) -- 256^2 would give only
//     128 blocks (half the CUs idle); revisit next round.
// Pipeline: prep -> qkv_proj8 (384 blk) -> scores8 (256 blk) -> PV (512 blk).
// ---------------------------------------------------------------------------

typedef __bf16 bf16_t;
typedef bf16_t bf16x8 __attribute__((ext_vector_type(8)));
typedef bf16_t bf16x4 __attribute__((ext_vector_type(4)));
typedef float  f32x4  __attribute__((ext_vector_type(4)));

typedef const __attribute__((address_space(1))) unsigned gl_uint;
typedef __attribute__((address_space(3))) unsigned lds_uint;

#define BM 128
#define BN 128
#define BK 64

__device__ __forceinline__ void gload_lds16(const void* g, void* l) {
  __builtin_amdgcn_global_load_lds((gl_uint*)g, (lds_uint*)l, 16, 0, 0);
}

#define VMCNT(N) asm volatile("s_waitcnt vmcnt(" #N ")" ::: "memory")
#define LGKM0()  asm volatile("s_waitcnt lgkmcnt(0)" ::: "memory")

// ===========================================================================
// 256x256 8-phase core (K multiple of 128). acc[8][4] per thread.
// LDS halves: buf*4+h, h: 0=A rows0-127, 1=A rows128-255, 2=B rows0-127,
// 3=B rows128-255; each 128x64 bf16 = 16KiB, XOR-swizzled 16B slots
// (slot c holds global seg c^(row&7)); staged linearly by global_load_lds.
// ===========================================================================
__device__ __forceinline__ void gemm256_8p(
    const bf16_t* __restrict__ Ab, const bf16_t* __restrict__ Bb,
    const int K, bf16_t* Lb, f32x4 acc[8][4])
{
  const int tid  = threadIdx.x;
  const int lane = tid & 63;
  const int l15  = lane & 15;
  const int quad = lane >> 4;
  const int wid  = tid >> 6;
  const int wr   = wid >> 2;     // 0..1  (M half)
  const int wc   = wid & 3;      // 0..3  (N quarter)
  const int swz0 = (quad ^ (l15 & 7)) * 8;        // kk=0 slot (elements)
  const int swz1 = ((quad + 4) ^ (l15 & 7)) * 8;  // kk=1 slot

  // staging: 2 issues x 512 thr x 16B = one 128x64 half. Same offsets for A/B
  // (both row-major stride K). Global source is pre-swizzled; LDS dest linear.
  const int r0  = tid >> 3, r1 = r0 + 64;
  const int so0 = r0 * K + (((tid & 7) ^ (r0 & 7)) * 8);
  const int so1 = r1 * K + (((tid & 7) ^ (r1 & 7)) * 8);
  const int sd0 = tid * 8, sd1 = 4096 + tid * 8;

#define HALF(buf, h) (Lb + ((buf) * 4 + (h)) * 8192)
#define STAGE(gsrc, buf, h) { const bf16_t* _g = (gsrc); bf16_t* _l = HALF(buf, h); \
    gload_lds16(_g + so0, _l + sd0); gload_lds16(_g + so1, _l + sd1); }

  const int aoff = l15 * 64;                      // + mi*1024 + swz
  const int boff = ((wc & 1) * 64 + l15) * 64;    // + ni*1024 + swz
  bf16x8 fa[4][2], fb[4][2];

#define RD_FB(buf) { const bf16_t* _B = HALF(buf, 2 + (wc >> 1)) + boff; \
  _Pragma("unroll") for (int ni = 0; ni < 4; ++ni) { \
    fb[ni][0] = *(const bf16x8*)(_B + ni * 1024 + swz0); \
    fb[ni][1] = *(const bf16x8*)(_B + ni * 1024 + swz1); } }
#define RD_FA(buf, MO) { const bf16_t* _A = HALF(buf, wr) + aoff + (MO) * 1024; \
  _Pragma("unroll") for (int mi = 0; mi < 4; ++mi) { \
    fa[mi][0] = *(const bf16x8*)(_A + mi * 1024 + swz0); \
    fa[mi][1] = *(const bf16x8*)(_A + mi * 1024 + swz1); } }

#define MFQ(MH, NL) \
  _Pragma("unroll") for (int kk = 0; kk < 2; ++kk) \
  _Pragma("unroll") for (int mi = 0; mi < 4; ++mi) \
  _Pragma("unroll") for (int ni = 0; ni < 2; ++ni) \
    acc[(MH) * 4 + mi][(NL) + ni] = __builtin_amdgcn_mfma_f32_16x16x32_bf16( \
        fa[mi][kk], fb[(NL) + ni][kk], acc[(MH) * 4 + mi][(NL) + ni], 0, 0, 0);

#define PH_PRE() __builtin_amdgcn_s_barrier(); LGKM0(); \
                 __builtin_amdgcn_sched_barrier(0); __builtin_amdgcn_s_setprio(1)
#define PH_POST() __builtin_amdgcn_s_setprio(0); __builtin_amdgcn_sched_barrier(0)

  const int NJ = K >> 7;            // iterations (2 K-tiles each)
  const size_t hk = (size_t)128 * K;  // A1/B1 half row offset

  // Prologue: stage kt0 {B0,B1,A0,A1} + kt1 {B0,B1,A0} = 7 halves (14 loads).
  STAGE(Bb,           0, 2);  STAGE(Bb + hk,      0, 3);
  STAGE(Ab,           0, 0);  STAGE(Ab + hk,      0, 1);
  STAGE(Bb + 64,      1, 2);  STAGE(Bb + hk + 64, 1, 3);
  STAGE(Ab + 64,      1, 0);
  VMCNT(6);                    // kt0 complete; kt1's 3 halves in flight
  __builtin_amdgcn_s_barrier();

  for (int j = 0; j < NJ - 1; ++j) {
    const int c1 = 2 * j * 64 + 64;       // (2j+1)*64
    const int c2 = c1 + 64, c3 = c2 + 64;
    // ph0: read fb(buf0)+fa_lo(buf0); stage A1(kt+1)->buf1 ; MFMA q(0,0)
    RD_FB(0); RD_FA(0, 0);
    STAGE(Ab + hk + c1, 1, 1);
    PH_PRE(); MFQ(0, 0); PH_POST(); __builtin_amdgcn_s_barrier();
    // ph1: stage B0(kt+2)->buf0 (buf0.B fully read in ph0) ; q(0,1)
    STAGE(Bb + c2, 0, 2);
    PH_PRE(); MFQ(0, 2); PH_POST(); __builtin_amdgcn_s_barrier();
    // ph2: read fa_hi(buf0); stage B1(kt+2) ; q(1,0)
    RD_FA(0, 4);
    STAGE(Bb + hk + c2, 0, 3);
    PH_PRE(); MFQ(1, 0); PH_POST(); __builtin_amdgcn_s_barrier();
    // ph3: stage A0(kt+2) (buf0.A read ph0+ph2) ; q(1,1) ; vmcnt(6): kt+1 ready
    STAGE(Ab + c2, 0, 0);
    PH_PRE(); MFQ(1, 2); PH_POST(); VMCNT(6); __builtin_amdgcn_s_barrier();
    // ph4: read fb(buf1)+fa_lo(buf1); stage A1(kt+2) ; q(0,0)
    RD_FB(1); RD_FA(1, 0);
    STAGE(Ab + hk + c2, 0, 1);
    PH_PRE(); MFQ(0, 0); PH_POST(); __builtin_amdgcn_s_barrier();
    // ph5: stage B0(kt+3)->buf1 ; q(0,1)
    STAGE(Bb + c3, 1, 2);
    PH_PRE(); MFQ(0, 2); PH_POST(); __builtin_amdgcn_s_barrier();
    // ph6: read fa_hi(buf1); stage B1(kt+3) ; q(1,0)
    RD_FA(1, 4);
    STAGE(Bb + hk + c3, 1, 3);
    PH_PRE(); MFQ(1, 0); PH_POST(); __builtin_amdgcn_s_barrier();
    // ph7: stage A0(kt+3) ; q(1,1) ; vmcnt(6): kt+2 ready
    STAGE(Ab + c3, 1, 0);
    PH_PRE(); MFQ(1, 2); PH_POST(); VMCNT(6); __builtin_amdgcn_s_barrier();
  }
  // Tail iteration: kt=NT-2 (buf0), kt+1=NT-1 (buf1); only A1(NT-1) left.
  {
    const int c1 = K - 64;  // (NT-1)*64
    RD_FB(0); RD_FA(0, 0);
    STAGE(Ab + hk + c1, 1, 1);
    PH_PRE(); MFQ(0, 0); PH_POST(); __builtin_amdgcn_s_barrier();
    PH_PRE(); MFQ(0, 2); PH_POST(); __builtin_amdgcn_s_barrier();
    RD_FA(0, 4);
    PH_PRE(); MFQ(1, 0); PH_POST(); __builtin_amdgcn_s_barrier();
    PH_PRE(); MFQ(1, 2); PH_POST(); VMCNT(0); __builtin_amdgcn_s_barrier();
    RD_FB(1); RD_FA(1, 0);
    PH_PRE(); MFQ(0, 0); PH_POST(); __builtin_amdgcn_s_barrier();
    PH_PRE(); MFQ(0, 2); PH_POST(); __builtin_amdgcn_s_barrier();
    RD_FA(1, 4);
    PH_PRE(); MFQ(1, 0); PH_POST(); __builtin_amdgcn_s_barrier();
    PH_PRE(); MFQ(1, 2); PH_POST();
  }
#undef HALF
#undef STAGE
#undef RD_FB
#undef RD_FA
#undef MFQ
#undef PH_PRE
#undef PH_POST
}

// Fused Q/K/V projection, 256x256 tiles: 3 z x 32 by x 4 bx = 384 blocks.
__global__ __launch_bounds__(512, 2)
void qkv_proj8(const bf16_t* __restrict__ qb, const bf16_t* __restrict__ kb,
               const bf16_t* __restrict__ vb, const bf16_t* __restrict__ Wqt,
               const bf16_t* __restrict__ Wkt, const bf16_t* __restrict__ Wvt,
               const float* __restrict__ bq, const float* __restrict__ bk,
               const float* __restrict__ bv, bf16_t* __restrict__ qp,
               bf16_t* __restrict__ kp, bf16_t* __restrict__ vT)
{
  __shared__ __align__(16) bf16_t lds[2 * 4 * 8192];   // 128 KiB
  const int L   = blockIdx.x;
  const int lin = (L & 7) * 48 + (L >> 3);   // XCD-contiguous, bijective (384%8==0)
  const int z   = lin >> 7;
  const int r   = lin & 127;
  const int by  = r >> 2, bx = r & 3;
  const int K = 1024, N = 1024;

  const bf16_t* A    = (z == 0) ? qb : (z == 1) ? kb : vb;
  const bf16_t* W    = (z == 0) ? Wqt : (z == 1) ? Wkt : Wvt;
  const float*  bias = (z == 0) ? bq : (z == 1) ? bk : bv;

  f32x4 acc[8][4];
  const f32x4 z4 = {0.f, 0.f, 0.f, 0.f};
#pragma unroll
  for (int i = 0; i < 8; ++i)
#pragma unroll
    for (int jj = 0; jj < 4; ++jj) acc[i][jj] = z4;

  gemm256_8p(A + (size_t)by * 256 * K, W + (size_t)bx * 256 * K, K, lds, acc);

  const int tid = threadIdx.x;
  const int lane = tid & 63, l15 = lane & 15, quad = lane >> 4;
  const int wid = tid >> 6, wr = wid >> 2, wc = wid & 3;
  const int m0 = by * 256 + wr * 128;
  const int n0 = bx * 256 + wc * 64;
  float bv_[4];
#pragma unroll
  for (int ni = 0; ni < 4; ++ni) bv_[ni] = bias[n0 + ni * 16 + l15];

  if (z < 2) {
    bf16_t* C = (z == 0) ? qp : kp;
#pragma unroll
    for (int mi = 0; mi < 8; ++mi) {
      const int gm = m0 + mi * 16 + quad * 4;
#pragma unroll
      for (int ni = 0; ni < 4; ++ni) {
        const int gn = n0 + ni * 16 + l15;
        f32x4 a = acc[mi][ni];
#pragma unroll
        for (int rr = 0; rr < 4; ++rr)
          C[(size_t)(gm + rr) * N + gn] = (bf16_t)(a[rr] + bv_[ni]);
      }
    }
  } else {
#pragma unroll
    for (int mi = 0; mi < 8; ++mi) {
      const int gm = m0 + mi * 16 + quad * 4;
      const int b = gm >> 11;   // S=2048
      const int s = gm & 2047;
#pragma unroll
      for (int ni = 0; ni < 4; ++ni) {
        const int gn = n0 + ni * 16 + l15;
        f32x4 a = acc[mi][ni];
        bf16x4 o;
#pragma unroll
        for (int rr = 0; rr < 4; ++rr) o[rr] = (bf16_t)(a[rr] + bv_[ni]);
        *(bf16x4*)&vT[((size_t)b * N + gn) * 2048 + s] = o;
      }
    }
  }
}

// scores: P = exp2(q.k^T * c), 256x256 tiles: 4 bz x 8 by x 8 bx = 256 blocks.
__global__ __launch_bounds__(512, 2)
void scores8(const bf16_t* __restrict__ qp, const bf16_t* __restrict__ kp,
             bf16_t* __restrict__ P)
{
  __shared__ __align__(16) bf16_t lds[2 * 4 * 8192];   // 128 KiB
  const int L   = blockIdx.x;
  const int lin = (L & 7) * 32 + (L >> 3);   // bijective (256%8==0)
  const int bz  = lin >> 6;
  const int r   = lin & 63;
  const int by  = r >> 3, bx = r & 7;
  const int K = 1024;

  const bf16_t* Ab = qp + (size_t)bz * 2048 * 1024 + (size_t)by * 256 * K;
  const bf16_t* Bb = kp + (size_t)bz * 2048 * 1024 + (size_t)bx * 256 * K;

  f32x4 acc[8][4];
  const f32x4 z4 = {0.f, 0.f, 0.f, 0.f};
#pragma unroll
  for (int i = 0; i < 8; ++i)
#pragma unroll
    for (int jj = 0; jj < 4; ++jj) acc[i][jj] = z4;

  gemm256_8p(Ab, Bb, K, lds, acc);

  const int tid = threadIdx.x;
  const int lane = tid & 63, l15 = lane & 15, quad = lane >> 4;
  const int wid = tid >> 6, wr = wid >> 2, wc = wid & 3;
  const int m0 = by * 256 + wr * 128;
  const int n0 = bx * 256 + wc * 64;
  bf16_t* C = P + (size_t)bz * 2048 * 2048;
  const float cexp = 0.03125f * 1.4426950408889634f;  // (1/32)*log2(e)
#pragma unroll
  for (int mi = 0; mi < 8; ++mi) {
    const int gm = m0 + mi * 16 + quad * 4;
#pragma unroll
    for (int ni = 0; ni < 4; ++ni) {
      const int gn = n0 + ni * 16 + l15;
      f32x4 a = acc[mi][ni];
#pragma unroll
      for (int rr = 0; rr < 4; ++rr)
        C[(size_t)(gm + rr) * 2048 + gn] = (bf16_t)exp2f(a[rr] * cexp);
    }
  }
}

// ===========================================================================
// R7 128x128 core (kept for PV) -- verified, conflict-free.
// ===========================================================================
template <bool LSUM>
__device__ __forceinline__ void mfma_tile(const bf16_t* As, const bf16_t* Bs,
                                          f32x4 acc[4][4], f32x4 acc_l[4]) {
  const int lane = threadIdx.x & 63;
  const int quad = lane >> 4;
  const int l15  = lane & 15;
  const int wid  = threadIdx.x >> 6;
  const int wm   = (wid >> 1) * 64;
  const int wn   = (wid & 1) * 64;
  const int csw  = l15 & 7;
  bf16x8 ones;
  if (LSUM) {
#pragma unroll
    for (int t = 0; t < 8; ++t) ones[t] = (bf16_t)1.0f;
  }
#pragma unroll
  for (int ks = 0; ks < 2; ++ks) {
    const int sg = ks * 4 + quad;
    const int c  = (sg ^ csw) * 8;
    bf16x8 fa[4], fb[4];
#pragma unroll
    for (int i = 0; i < 4; ++i)
      fa[i] = *(const bf16x8*)&As[(wm + i * 16 + l15) * BK + c];
#pragma unroll
    for (int i = 0; i < 4; ++i)
      fb[i] = *(const bf16x8*)&Bs[(wn + i * 16 + l15) * BK + c];
#pragma unroll
    for (int mi = 0; mi < 4; ++mi)
#pragma unroll
      for (int ni = 0; ni < 4; ++ni)
        acc[mi][ni] = __builtin_amdgcn_mfma_f32_16x16x32_bf16(
            fa[mi], fb[ni], acc[mi][ni], 0, 0, 0);
    if (LSUM) {
#pragma unroll
      for (int mi = 0; mi < 4; ++mi)
        acc_l[mi] = __builtin_amdgcn_mfma_f32_16x16x32_bf16(
            fa[mi], ones, acc_l[mi], 0, 0, 0);
    }
  }
}

template <bool LSUM>
__device__ __forceinline__ void gemm_core_bf16(
    const bf16_t* __restrict__ Ab, const bf16_t* __restrict__ Bb,
    const int K, bf16_t* As, bf16_t* Bs, f32x4 acc[4][4], f32x4 acc_l[4])
{
  const int tid = threadIdx.x;
  for (int kt = 0; kt < K; kt += BK) {
#pragma unroll
    for (int j = 0; j < 4; ++j) {
      const int lin = j * 256 + tid;
      const int row = lin >> 3;
      const int seg = (lin & 7) ^ (row & 7);
      gload_lds16(Ab + (size_t)row * K + kt + seg * 8, &As[lin * 8]);
    }
#pragma unroll
    for (int j = 0; j < 4; ++j) {
      const int lin = j * 256 + tid;
      const int row = lin >> 3;
      const int seg = (lin & 7) ^ (row & 7);
      gload_lds16(Bb + (size_t)row * K + kt + seg * 8, &Bs[lin * 8]);
    }
    __syncthreads();
    mfma_tile<LSUM>(As, Bs, acc, acc_l);
    __syncthreads();
  }
}

// MODE 1: PV (512 blocks) — C fp32 = acc / rowsum, rowsum via ones-MFMA.
template <int MODE>
__global__ __launch_bounds__(256, 2)
void gemm_att(const bf16_t* __restrict__ A, const bf16_t* __restrict__ Bt,
              void* __restrict__ Cv,
              const int M, const int N, const int K,
              const long long sA, const long long sB, const long long sC)
{
  __shared__ __align__(16) bf16_t As[BM * BK];
  __shared__ __align__(16) bf16_t Bs[BN * BK];

  const int L = blockIdx.x;
  int bx, by, bz;
  if (MODE == 0) {
    const int g = L >> 3;
    const int gst = (L & 7) * 2 + (g >> 6);
    bz = gst >> 2;
    const int s2 = gst & 3;
    const int w = g & 63;
    bx = (s2 & 1) * 8 + (w & 7);
    by = (s2 >> 1) * 8 + (w >> 3);
  } else {
    const int xcd = L & 7;
    const int w = (L >> 3) & 63;
    bz = xcd >> 1;
    bx = w & 7;
    by = (xcd & 1) * 8 + (w >> 3);
  }

  const bf16_t* Ab = A + (size_t)bz * sA + (size_t)by * BM * K;
  const bf16_t* Bb = Bt + (size_t)bz * sB + (size_t)bx * BN * K;

  f32x4 acc[4][4];
  f32x4 acc_l[4];
  const f32x4 z4 = {0.f, 0.f, 0.f, 0.f};
#pragma unroll
  for (int i = 0; i < 4; ++i) {
    acc_l[i] = z4;
#pragma unroll
    for (int j = 0; j < 4; ++j) acc[i][j] = z4;
  }

  gemm_core_bf16<MODE == 1>(Ab, Bb, K, As, Bs, acc, acc_l);

  const int lane = threadIdx.x & 63;
  const int quad = lane >> 4;
  const int l15  = lane & 15;
  const int wid  = threadIdx.x >> 6;
  const int wm = (wid >> 1) * 64, wn = (wid & 1) * 64;
  const int m0 = by * BM, n0 = bx * BN;

  if (MODE == 0) {
    const float cexp = 0.03125f * 1.4426950408889634f;
    bf16_t* C = (bf16_t*)Cv + (size_t)bz * sC;
#pragma unroll
    for (int mi = 0; mi < 4; ++mi) {
      const int gm = m0 + wm + mi * 16 + quad * 4;
#pragma unroll
      for (int ni = 0; ni < 4; ++ni) {
        const int gn = n0 + wn + ni * 16 + l15;
        f32x4 a = acc[mi][ni];
#pragma unroll
        for (int r = 0; r < 4; ++r)
          C[(size_t)(gm + r) * N + gn] = (bf16_t)exp2f(a[r] * cexp);
      }
    }
  } else {
    float* C = (float*)Cv + (size_t)bz * sC;
#pragma unroll
    for (int mi = 0; mi < 4; ++mi) {
      const int gm = m0 + wm + mi * 16 + quad * 4;
      float il[4];
#pragma unroll
      for (int r = 0; r < 4; ++r) il[r] = 1.0f / acc_l[mi][r];
#pragma unroll
      for (int ni = 0; ni < 4; ++ni) {
        const int gn = n0 + wn + ni * 16 + l15;
        f32x4 a = acc[mi][ni];
#pragma unroll
        for (int r = 0; r < 4; ++r)
          C[(size_t)(gm + r) * N + gn] = a[r] * il[r];
      }
    }
  }
}

// Merged prep: blocks [0,24576): fp32->bf16 cvt of q/k/v (1024 elem/block);
// blocks [24576,25344): 64x64 transpose-cvt tiles of Wq/Wk/Wv.
__global__ __launch_bounds__(256)
void prep(const float* __restrict__ q, const float* __restrict__ k,
          const float* __restrict__ v, const float* __restrict__ Wq,
          const float* __restrict__ Wk, const float* __restrict__ Wv,
          bf16_t* __restrict__ qo, bf16_t* __restrict__ ko,
          bf16_t* __restrict__ vo, bf16_t* __restrict__ Wqt,
          bf16_t* __restrict__ Wkt, bf16_t* __restrict__ Wvt) {
  const int L = blockIdx.x;
  const int tid = threadIdx.x;
  if (L < 24576) {
    const int z = L >> 13;
    const int blk = L & 8191;
    const float* in = (z == 0) ? q : (z == 1) ? k : v;
    bf16_t* out = (z == 0) ? qo : (z == 1) ? ko : vo;
    const size_t i = ((size_t)blk * 256 + tid) * 4;
    const float4 w = *(const float4*)(in + i);
    bf16x4 o;
    o[0] = (bf16_t)w.x; o[1] = (bf16_t)w.y; o[2] = (bf16_t)w.z; o[3] = (bf16_t)w.w;
    *(bf16x4*)(out + i) = o;
  } else {
    const int t = L - 24576;
    const int z = t >> 8;
    const int wi = t & 255;
    const float* W = (z == 0) ? Wq : (z == 1) ? Wk : Wv;
    bf16_t* Wt = (z == 0) ? Wqt : (z == 1) ? Wkt : Wvt;
    __shared__ float tile[64][65];
    const int n0 = (wi & 15) * 64;
    const int k0 = (wi >> 4) * 64;
#pragma unroll
    for (int it = 0; it < 16; ++it) {
      const int idx = it * 256 + tid;
      const int r = idx >> 6, c = idx & 63;
      tile[r][c] = W[(size_t)(k0 + r) * 1024 + n0 + c];
    }
    __syncthreads();
#pragma unroll
    for (int it = 0; it < 16; ++it) {
      const int idx = it * 256 + tid;
      const int r = idx >> 6, c = idx & 63;
      Wt[(size_t)(n0 + r) * 1024 + k0 + c] = (bf16_t)tile[c][r];
    }
  }
}

extern "C" void kernel_launch(void* const* d_in, const int* in_sizes, int n_in,
                              void* d_out, int out_size, void* d_ws, size_t ws_size,
                              hipStream_t stream) {
  const int B = 4, S = 2048, E = 1024;
  const size_t BSE = (size_t)B * S * E;
  const size_t EE  = (size_t)E * E;

  const float* q_in = (const float*)d_in[0];
  const float* k_in = (const float*)d_in[1];
  const float* v_in = (const float*)d_in[2];
  const float* Wq = (const float*)d_in[3];
  const float* bq = (const float*)d_in[4];
  const float* Wk = (const float*)d_in[5];
  const float* bk = (const float*)d_in[6];
  const float* Wv = (const float*)d_in[7];
  const float* bv = (const float*)d_in[8];
  float* out = (float*)d_out;

  char* ws = (char*)d_ws;
  bf16_t* Wqt = (bf16_t*)ws;                      // 2MB each
  bf16_t* Wkt = Wqt + EE;
  bf16_t* Wvt = Wkt + EE;
  bf16_t* qb  = Wvt + EE;                         // 16.8MB each
  bf16_t* kb  = qb + BSE;
  bf16_t* vb  = kb + BSE;
  bf16_t* qp  = vb + BSE;
  bf16_t* kp  = qp + BSE;
  bf16_t* vT  = kp + BSE;                         // [B][E][S]
  bf16_t* P   = vT + BSE;                         // [B][S][S] 33.5MB; ~140MB

  prep<<<25344, 256, 0, stream>>>(q_in, k_in, v_in, Wq, Wk, Wv,
                                  qb, kb, vb, Wqt, Wkt, Wvt);

  qkv_proj8<<<384, 512, 0, stream>>>(qb, kb, vb, Wqt, Wkt, Wvt,
                                     bq, bk, bv, qp, kp, vT);

  scores8<<<256, 512, 0, stream>>>(qp, kp, P);

  gemm_att<1><<<512, 256, 0, stream>>>(
      P, vT, out, S, E, S,
      (long long)S * S, (long long)E * S, (long long)S * E);

  (void)in_sizes; (void)n_in; (void)out_size; (void)ws_size;
}

// Round 3
// 283.951 us; speedup vs baseline: 1.0435x; 1.0435x over previous
//
#include <hip/hip_runtime.h>
#include <hip/hip_bf16.h>

// ---------------------------------------------------------------------------
// AttentionModel B=4,S=2048,E=1024 single-head, fp32 in/out. bf16 MFMA GEMMs.
// R10: qkv+scores on a 256x128-tile, 3-slot LDS ring, frag-double-buffered,
//      counted-vmcnt pipeline (NT=16 fully unrolled, all indices static):
//      iter kt: STAGE(kt+3 -> slot[kt%3])  (slot dead 1 iter + barrier)
//               RD frags(kt+1)             (used next iter -> counted lgkm)
//               MFMA(kt) from regs         (zero exposed LDS latency)
//               VMCNT(6); s_barrier        (kt+2 landed, kt+3 in flight)
//      R9 lesson: 8-phase with read-then-immediately-drain exposed all LDS
//      time (per-block util stuck at 37%) + 384-block grid wasted a half
//      round. Grids now quantize exactly: qkv 768 = 3 rounds, scores 512 = 2.
//      Fragment math + XOR-slot swizzle byte-identical to verified R7.
// Pipeline: prep -> qkv_v3 (768 blk) -> scores_v3 (512 blk) -> PV (512 blk).
// ---------------------------------------------------------------------------

typedef __bf16 bf16_t;
typedef bf16_t bf16x8 __attribute__((ext_vector_type(8)));
typedef bf16_t bf16x4 __attribute__((ext_vector_type(4)));
typedef float  f32x4  __attribute__((ext_vector_type(4)));

typedef const __attribute__((address_space(1))) unsigned gl_uint;
typedef __attribute__((address_space(3))) unsigned lds_uint;

#define BM 128
#define BN 128
#define BK 64

__device__ __forceinline__ void gload_lds16(const void* g, void* l) {
  __builtin_amdgcn_global_load_lds((gl_uint*)g, (lds_uint*)l, 16, 0, 0);
}

#define VMCNT(N) asm volatile("s_waitcnt vmcnt(" #N ")" ::: "memory")
#define LGKM0()  asm volatile("s_waitcnt lgkmcnt(0)" ::: "memory")

// ===========================================================================
// v3 core: 256x128 tile, K=1024 (NT=16 k-tiles of 64), 512 threads (8 waves
// as 4Mx2N, per-wave 64x64, acc[4][4]). LDS: 3 ring slots x (A 256x64 +
// B 128x64) = 144 KiB. Rows are 64 bf16 = 128 B = 8 x 16B slots, XOR-swizzled
// (slot c holds global seg c^(row&7)) -- verified conflict-free (R2/R7).
// Stage: 6 x global_load_lds(16B) per k-tile (A=4 units, B=2 units of 8KB).
// ===========================================================================
__device__ __forceinline__ void gemm_v3(
    const bf16_t* __restrict__ Ab, const bf16_t* __restrict__ Bb,
    bf16_t* Lb, f32x4 acc[4][4])
{
  const int tid  = threadIdx.x;
  const int lane = tid & 63;
  const int l15  = lane & 15;
  const int quad = lane >> 4;
  const int wid  = tid >> 6;
  const int wr   = wid >> 1;          // 0..3 (M quarter, 64 rows)
  const int wcl  = wid & 1;           // 0..1 (N half, 64 cols)
  const int swz0 = (quad ^ (l15 & 7)) * 8;
  const int swz1 = ((quad + 4) ^ (l15 & 7)) * 8;

  // Staging offsets: unit = 64 rows (8KB). row = u*64 + (tid>>3);
  // seg = (tid&7)^(row&7) = (tid&7)^((tid>>3)&7) since 64%8==0.
  const int r8 = tid >> 3, s8 = tid & 7;
  const size_t gbase = (size_t)r8 * 1024 + (size_t)((s8 ^ (r8 & 7)) * 8);
  const int dbase = tid * 8;          // elements (16B per thread)

  // slot s: A at s*24576, B at s*24576+16384 (elements)
#define SLOTA(s) (Lb + (s) * 24576)
#define SLOTB(s) (Lb + (s) * 24576 + 16384)
#define STAGE6(ktile, slot) { \
    const bf16_t* _A = Ab + (size_t)(ktile) * 64; \
    const bf16_t* _B = Bb + (size_t)(ktile) * 64; \
    bf16_t* _la = SLOTA(slot); bf16_t* _lb = SLOTB(slot); \
    gload_lds16(_A + gbase,                     _la + dbase); \
    gload_lds16(_A + gbase + (size_t)64 * 1024, _la + dbase + 4096); \
    gload_lds16(_A + gbase + (size_t)128 * 1024, _la + dbase + 8192); \
    gload_lds16(_A + gbase + (size_t)192 * 1024, _la + dbase + 12288); \
    gload_lds16(_B + gbase,                     _lb + dbase); \
    gload_lds16(_B + gbase + (size_t)64 * 1024, _lb + dbase + 4096); }

  const int aoff = (wr * 64 + l15) * 64;
  const int boff = (wcl * 64 + l15) * 64;

#define RD(slot, FA, FB) { \
    const bf16_t* _a = SLOTA(slot) + aoff; \
    const bf16_t* _b = SLOTB(slot) + boff; \
    _Pragma("unroll") for (int mi = 0; mi < 4; ++mi) { \
      FA[mi][0] = *(const bf16x8*)(_a + mi * 1024 + swz0); \
      FA[mi][1] = *(const bf16x8*)(_a + mi * 1024 + swz1); } \
    _Pragma("unroll") for (int ni = 0; ni < 4; ++ni) { \
      FB[ni][0] = *(const bf16x8*)(_b + ni * 1024 + swz0); \
      FB[ni][1] = *(const bf16x8*)(_b + ni * 1024 + swz1); } }

#define MFM(FA, FB) \
    _Pragma("unroll") for (int kk = 0; kk < 2; ++kk) \
    _Pragma("unroll") for (int mi = 0; mi < 4; ++mi) \
    _Pragma("unroll") for (int ni = 0; ni < 4; ++ni) \
      acc[mi][ni] = __builtin_amdgcn_mfma_f32_16x16x32_bf16( \
          FA[mi][kk], FB[ni][kk], acc[mi][ni], 0, 0, 0);

  bf16x8 fa0[4][2], fb0[4][2], fa1[4][2], fb1[4][2];

  // Prologue: stage k-tiles 0,1,2 into slots 0,1,2 (18 loads).
  STAGE6(0, 0); STAGE6(1, 1); STAGE6(2, 2);
  VMCNT(6);                         // tiles 0,1 landed; tile 2 in flight
  __builtin_amdgcn_s_barrier();
  RD(0, fa0, fb0);                  // frags(0)
  LGKM0();                          // drain so kt=0's stage can't clobber
  __builtin_amdgcn_s_barrier();

  // Main loop kt = 0..13 (fully unrolled; all slot / parity / predicates
  // fold to compile-time). Reads are one k-tile ahead; stage three ahead.
#pragma unroll
  for (int kt = 0; kt < 14; ++kt) {
    const int ss = kt % 3;          // stage slot (holds kt, dead since kt-1)
    const int rs = (kt + 1) % 3;    // read slot (kt+1, landed+barrier'd)
    if (kt <= 12) STAGE6(kt + 3, ss);
    if ((kt & 1) == 0) { RD(rs, fa1, fb1); MFM(fa0, fb0); }
    else               { RD(rs, fa0, fb0); MFM(fa1, fb1); }
    if (kt <= 12) { VMCNT(6); }     // kt+2 landed; kt+3 stays in flight
    else          { VMCNT(0); }     // kt=13: tile 15 landed (2-iter flight)
    __builtin_amdgcn_s_barrier();
  }
  // kt=14: read frags(15) (slot 15%3=0, landed), MFMA frags(14) (set0).
  RD(0, fa1, fb1); MFM(fa0, fb0);
  // kt=15: MFMA frags(15).
  MFM(fa1, fb1);

#undef SLOTA
#undef SLOTB
#undef STAGE6
#undef RD
#undef MFM
}

// Fused Q/K/V projection, 256x128 tiles: 3 z x 32 by x 8 bx = 768 blocks
// (= 3 exact dispatch rounds at 1 block/CU).
__global__ __launch_bounds__(512, 2)
void qkv_v3(const bf16_t* __restrict__ qb, const bf16_t* __restrict__ kb,
            const bf16_t* __restrict__ vb, const bf16_t* __restrict__ Wqt,
            const bf16_t* __restrict__ Wkt, const bf16_t* __restrict__ Wvt,
            const float* __restrict__ bq, const float* __restrict__ bk,
            const float* __restrict__ bv, bf16_t* __restrict__ qp,
            bf16_t* __restrict__ kp, bf16_t* __restrict__ vT)
{
  __shared__ __align__(16) bf16_t lds[3 * 24576];   // 144 KiB
  const int L   = blockIdx.x;
  const int lin = (L & 7) * 96 + (L >> 3);   // XCD-contiguous, bijective
  const int z   = lin >> 8;                  // 256 tiles per z
  const int r   = lin & 255;
  const int by  = r >> 3, bx = r & 7;
  const int K = 1024, N = 1024;

  const bf16_t* A    = (z == 0) ? qb : (z == 1) ? kb : vb;
  const bf16_t* W    = (z == 0) ? Wqt : (z == 1) ? Wkt : Wvt;
  const float*  bias = (z == 0) ? bq : (z == 1) ? bk : bv;

  f32x4 acc[4][4];
  const f32x4 z4 = {0.f, 0.f, 0.f, 0.f};
#pragma unroll
  for (int i = 0; i < 4; ++i)
#pragma unroll
    for (int j = 0; j < 4; ++j) acc[i][j] = z4;

  gemm_v3(A + (size_t)by * 256 * K, W + (size_t)bx * 128 * K, lds, acc);

  const int tid = threadIdx.x;
  const int lane = tid & 63, l15 = lane & 15, quad = lane >> 4;
  const int wid = tid >> 6, wr = wid >> 1, wcl = wid & 1;
  const int m0 = by * 256 + wr * 64;
  const int n0 = bx * 128 + wcl * 64;
  float bv_[4];
#pragma unroll
  for (int ni = 0; ni < 4; ++ni) bv_[ni] = bias[n0 + ni * 16 + l15];

  if (z < 2) {
    bf16_t* C = (z == 0) ? qp : kp;
#pragma unroll
    for (int mi = 0; mi < 4; ++mi) {
      const int gm = m0 + mi * 16 + quad * 4;
#pragma unroll
      for (int ni = 0; ni < 4; ++ni) {
        const int gn = n0 + ni * 16 + l15;
        f32x4 a = acc[mi][ni];
#pragma unroll
        for (int rr = 0; rr < 4; ++rr)
          C[(size_t)(gm + rr) * N + gn] = (bf16_t)(a[rr] + bv_[ni]);
      }
    }
  } else {
#pragma unroll
    for (int mi = 0; mi < 4; ++mi) {
      const int gm = m0 + mi * 16 + quad * 4;
      const int b = gm >> 11;   // S=2048
      const int s = gm & 2047;
#pragma unroll
      for (int ni = 0; ni < 4; ++ni) {
        const int gn = n0 + ni * 16 + l15;
        f32x4 a = acc[mi][ni];
        bf16x4 o;
#pragma unroll
        for (int rr = 0; rr < 4; ++rr) o[rr] = (bf16_t)(a[rr] + bv_[ni]);
        *(bf16x4*)&vT[((size_t)b * N + gn) * 2048 + s] = o;
      }
    }
  }
}

// scores: P = exp2(q.k^T * c), 256x128 tiles: 4 bz x 8 by x 16 bx = 512
// blocks (= 2 exact dispatch rounds).
__global__ __launch_bounds__(512, 2)
void scores_v3(const bf16_t* __restrict__ qp, const bf16_t* __restrict__ kp,
               bf16_t* __restrict__ P)
{
  __shared__ __align__(16) bf16_t lds[3 * 24576];   // 144 KiB
  const int L   = blockIdx.x;
  const int lin = (L & 7) * 64 + (L >> 3);   // bijective (512%8==0)
  const int bz  = lin >> 7;
  const int r   = lin & 127;
  const int by  = r >> 4, bx = r & 15;
  const int K = 1024;

  const bf16_t* Ab = qp + (size_t)bz * 2048 * 1024 + (size_t)by * 256 * K;
  const bf16_t* Bb = kp + (size_t)bz * 2048 * 1024 + (size_t)bx * 128 * K;

  f32x4 acc[4][4];
  const f32x4 z4 = {0.f, 0.f, 0.f, 0.f};
#pragma unroll
  for (int i = 0; i < 4; ++i)
#pragma unroll
    for (int j = 0; j < 4; ++j) acc[i][j] = z4;

  gemm_v3(Ab, Bb, lds, acc);

  const int tid = threadIdx.x;
  const int lane = tid & 63, l15 = lane & 15, quad = lane >> 4;
  const int wid = tid >> 6, wr = wid >> 1, wcl = wid & 1;
  const int m0 = by * 256 + wr * 64;
  const int n0 = bx * 128 + wcl * 64;
  bf16_t* C = P + (size_t)bz * 2048 * 2048;
  const float cexp = 0.03125f * 1.4426950408889634f;  // (1/32)*log2(e)
#pragma unroll
  for (int mi = 0; mi < 4; ++mi) {
    const int gm = m0 + mi * 16 + quad * 4;
#pragma unroll
    for (int ni = 0; ni < 4; ++ni) {
      const int gn = n0 + ni * 16 + l15;
      f32x4 a = acc[mi][ni];
#pragma unroll
      for (int rr = 0; rr < 4; ++rr)
        C[(size_t)(gm + rr) * 2048 + gn] = (bf16_t)exp2f(a[rr] * cexp);
    }
  }
}

// ===========================================================================
// R7 128x128 core (kept for PV) -- verified, conflict-free.
// ===========================================================================
template <bool LSUM>
__device__ __forceinline__ void mfma_tile(const bf16_t* As, const bf16_t* Bs,
                                          f32x4 acc[4][4], f32x4 acc_l[4]) {
  const int lane = threadIdx.x & 63;
  const int quad = lane >> 4;
  const int l15  = lane & 15;
  const int wid  = threadIdx.x >> 6;
  const int wm   = (wid >> 1) * 64;
  const int wn   = (wid & 1) * 64;
  const int csw  = l15 & 7;
  bf16x8 ones;
  if (LSUM) {
#pragma unroll
    for (int t = 0; t < 8; ++t) ones[t] = (bf16_t)1.0f;
  }
#pragma unroll
  for (int ks = 0; ks < 2; ++ks) {
    const int sg = ks * 4 + quad;
    const int c  = (sg ^ csw) * 8;
    bf16x8 fa[4], fb[4];
#pragma unroll
    for (int i = 0; i < 4; ++i)
      fa[i] = *(const bf16x8*)&As[(wm + i * 16 + l15) * BK + c];
#pragma unroll
    for (int i = 0; i < 4; ++i)
      fb[i] = *(const bf16x8*)&Bs[(wn + i * 16 + l15) * BK + c];
#pragma unroll
    for (int mi = 0; mi < 4; ++mi)
#pragma unroll
      for (int ni = 0; ni < 4; ++ni)
        acc[mi][ni] = __builtin_amdgcn_mfma_f32_16x16x32_bf16(
            fa[mi], fb[ni], acc[mi][ni], 0, 0, 0);
    if (LSUM) {
#pragma unroll
      for (int mi = 0; mi < 4; ++mi)
        acc_l[mi] = __builtin_amdgcn_mfma_f32_16x16x32_bf16(
            fa[mi], ones, acc_l[mi], 0, 0, 0);
    }
  }
}

template <bool LSUM>
__device__ __forceinline__ void gemm_core_bf16(
    const bf16_t* __restrict__ Ab, const bf16_t* __restrict__ Bb,
    const int K, bf16_t* As, bf16_t* Bs, f32x4 acc[4][4], f32x4 acc_l[4])
{
  const int tid = threadIdx.x;
  for (int kt = 0; kt < K; kt += BK) {
#pragma unroll
    for (int j = 0; j < 4; ++j) {
      const int lin = j * 256 + tid;
      const int row = lin >> 3;
      const int seg = (lin & 7) ^ (row & 7);
      gload_lds16(Ab + (size_t)row * K + kt + seg * 8, &As[lin * 8]);
    }
#pragma unroll
    for (int j = 0; j < 4; ++j) {
      const int lin = j * 256 + tid;
      const int row = lin >> 3;
      const int seg = (lin & 7) ^ (row & 7);
      gload_lds16(Bb + (size_t)row * K + kt + seg * 8, &Bs[lin * 8]);
    }
    __syncthreads();
    mfma_tile<LSUM>(As, Bs, acc, acc_l);
    __syncthreads();
  }
}

// MODE 1: PV (512 blocks) — C fp32 = acc / rowsum, rowsum via ones-MFMA.
template <int MODE>
__global__ __launch_bounds__(256, 2)
void gemm_att(const bf16_t* __restrict__ A, const bf16_t* __restrict__ Bt,
              void* __restrict__ Cv,
              const int M, const int N, const int K,
              const long long sA, const long long sB, const long long sC)
{
  __shared__ __align__(16) bf16_t As[BM * BK];
  __shared__ __align__(16) bf16_t Bs[BN * BK];

  const int L = blockIdx.x;
  int bx, by, bz;
  if (MODE == 0) {
    const int g = L >> 3;
    const int gst = (L & 7) * 2 + (g >> 6);
    bz = gst >> 2;
    const int s2 = gst & 3;
    const int w = g & 63;
    bx = (s2 & 1) * 8 + (w & 7);
    by = (s2 >> 1) * 8 + (w >> 3);
  } else {
    const int xcd = L & 7;
    const int w = (L >> 3) & 63;
    bz = xcd >> 1;
    bx = w & 7;
    by = (xcd & 1) * 8 + (w >> 3);
  }

  const bf16_t* Ab = A + (size_t)bz * sA + (size_t)by * BM * K;
  const bf16_t* Bb = Bt + (size_t)bz * sB + (size_t)bx * BN * K;

  f32x4 acc[4][4];
  f32x4 acc_l[4];
  const f32x4 z4 = {0.f, 0.f, 0.f, 0.f};
#pragma unroll
  for (int i = 0; i < 4; ++i) {
    acc_l[i] = z4;
#pragma unroll
    for (int j = 0; j < 4; ++j) acc[i][j] = z4;
  }

  gemm_core_bf16<MODE == 1>(Ab, Bb, K, As, Bs, acc, acc_l);

  const int lane = threadIdx.x & 63;
  const int quad = lane >> 4;
  const int l15  = lane & 15;
  const int wid  = threadIdx.x >> 6;
  const int wm = (wid >> 1) * 64, wn = (wid & 1) * 64;
  const int m0 = by * BM, n0 = bx * BN;

  if (MODE == 0) {
    const float cexp = 0.03125f * 1.4426950408889634f;
    bf16_t* C = (bf16_t*)Cv + (size_t)bz * sC;
#pragma unroll
    for (int mi = 0; mi < 4; ++mi) {
      const int gm = m0 + wm + mi * 16 + quad * 4;
#pragma unroll
      for (int ni = 0; ni < 4; ++ni) {
        const int gn = n0 + wn + ni * 16 + l15;
        f32x4 a = acc[mi][ni];
#pragma unroll
        for (int r = 0; r < 4; ++r)
          C[(size_t)(gm + r) * N + gn] = (bf16_t)exp2f(a[r] * cexp);
      }
    }
  } else {
    float* C = (float*)Cv + (size_t)bz * sC;
#pragma unroll
    for (int mi = 0; mi < 4; ++mi) {
      const int gm = m0 + wm + mi * 16 + quad * 4;
      float il[4];
#pragma unroll
      for (int r = 0; r < 4; ++r) il[r] = 1.0f / acc_l[mi][r];
#pragma unroll
      for (int ni = 0; ni < 4; ++ni) {
        const int gn = n0 + wn + ni * 16 + l15;
        f32x4 a = acc[mi][ni];
#pragma unroll
        for (int r = 0; r < 4; ++r)
          C[(size_t)(gm + r) * N + gn] = a[r] * il[r];
      }
    }
  }
}

// Merged prep: blocks [0,24576): fp32->bf16 cvt of q/k/v (1024 elem/block);
// blocks [24576,25344): 64x64 transpose-cvt tiles of Wq/Wk/Wv.
__global__ __launch_bounds__(256)
void prep(const float* __restrict__ q, const float* __restrict__ k,
          const float* __restrict__ v, const float* __restrict__ Wq,
          const float* __restrict__ Wk, const float* __restrict__ Wv,
          bf16_t* __restrict__ qo, bf16_t* __restrict__ ko,
          bf16_t* __restrict__ vo, bf16_t* __restrict__ Wqt,
          bf16_t* __restrict__ Wkt, bf16_t* __restrict__ Wvt) {
  const int L = blockIdx.x;
  const int tid = threadIdx.x;
  if (L < 24576) {
    const int z = L >> 13;
    const int blk = L & 8191;
    const float* in = (z == 0) ? q : (z == 1) ? k : v;
    bf16_t* out = (z == 0) ? qo : (z == 1) ? ko : vo;
    const size_t i = ((size_t)blk * 256 + tid) * 4;
    const float4 w = *(const float4*)(in + i);
    bf16x4 o;
    o[0] = (bf16_t)w.x; o[1] = (bf16_t)w.y; o[2] = (bf16_t)w.z; o[3] = (bf16_t)w.w;
    *(bf16x4*)(out + i) = o;
  } else {
    const int t = L - 24576;
    const int z = t >> 8;
    const int wi = t & 255;
    const float* W = (z == 0) ? Wq : (z == 1) ? Wk : Wv;
    bf16_t* Wt = (z == 0) ? Wqt : (z == 1) ? Wkt : Wvt;
    __shared__ float tile[64][65];
    const int n0 = (wi & 15) * 64;
    const int k0 = (wi >> 4) * 64;
#pragma unroll
    for (int it = 0; it < 16; ++it) {
      const int idx = it * 256 + tid;
      const int r = idx >> 6, c = idx & 63;
      tile[r][c] = W[(size_t)(k0 + r) * 1024 + n0 + c];
    }
    __syncthreads();
#pragma unroll
    for (int it = 0; it < 16; ++it) {
      const int idx = it * 256 + tid;
      const int r = idx >> 6, c = idx & 63;
      Wt[(size_t)(n0 + r) * 1024 + k0 + c] = (bf16_t)tile[c][r];
    }
  }
}

extern "C" void kernel_launch(void* const* d_in, const int* in_sizes, int n_in,
                              void* d_out, int out_size, void* d_ws, size_t ws_size,
                              hipStream_t stream) {
  const int B = 4, S = 2048, E = 1024;
  const size_t BSE = (size_t)B * S * E;
  const size_t EE  = (size_t)E * E;

  const float* q_in = (const float*)d_in[0];
  const float* k_in = (const float*)d_in[1];
  const float* v_in = (const float*)d_in[2];
  const float* Wq = (const float*)d_in[3];
  const float* bq = (const float*)d_in[4];
  const float* Wk = (const float*)d_in[5];
  const float* bk = (const float*)d_in[6];
  const float* Wv = (const float*)d_in[7];
  const float* bv = (const float*)d_in[8];
  float* out = (float*)d_out;

  char* ws = (char*)d_ws;
  bf16_t* Wqt = (bf16_t*)ws;                      // 2MB each
  bf16_t* Wkt = Wqt + EE;
  bf16_t* Wvt = Wkt + EE;
  bf16_t* qb  = Wvt + EE;                         // 16.8MB each
  bf16_t* kb  = qb + BSE;
  bf16_t* vb  = kb + BSE;
  bf16_t* qp  = vb + BSE;
  bf16_t* kp  = qp + BSE;
  bf16_t* vT  = kp + BSE;                         // [B][E][S]
  bf16_t* P   = vT + BSE;                         // [B][S][S] 33.5MB; ~140MB

  prep<<<25344, 256, 0, stream>>>(q_in, k_in, v_in, Wq, Wk, Wv,
                                  qb, kb, vb, Wqt, Wkt, Wvt);

  qkv_v3<<<768, 512, 0, stream>>>(qb, kb, vb, Wqt, Wkt, Wvt,
                                  bq, bk, bv, qp, kp, vT);

  scores_v3<<<512, 512, 0, stream>>>(qp, kp, P);

  gemm_att<1><<<512, 256, 0, stream>>>(
      P, vT, out, S, E, S,
      (long long)S * S, (long long)E * S, (long long)S * E);

  (void)in_sizes; (void)n_in; (void)out_size; (void)ws_size;
}